// Round 10
// baseline (2011.240 us; speedup 1.0000x reference)
//
#include <hip/hip_runtime.h>

// Residual VQ: B=32, D=64, L=4096, NCB=4, K=512.
// out: z_q_aggregated [B][NCB][D][L] f32, then indices [B][L][NCB] (as f32).
//
// Bit-exact reproduction of the reference float32 pipeline (validated absmax=0):
//   dot[t][k]: mul-init + single-accumulator FMA chain, d ascending 0..63
//   sx, se:    numpy pairwise 8-accumulator sum of squares, exact bracketing
//   d2 = (sx - 2*dot) + se     (two f32 roundings; 2*dot exact)
//   argmin:    first minimum (lowest k)
//   cascade:   x_res -= e[idx]; z_q += e[idx] in plain f32
//
// v10: v9's k-split-x2 structure (wave pairs share 64 tokens; A scans k<256,
// B scans k>=256; LDS merge with index tie-break == global first-min; zq in
// LDS for A-waves; 1024 blocks = 4 blocks/CU, proven resident in v9 at 46.9%
// occupancy) WITHOUT the launch_bounds(,4) VGPR cap: v9's forced 64-VGPR
// allocation spilled x[64] to scratch (WRITE 137->200MB, VALUBusy 26%).
// v7/v8 allocated 84 VGPR naturally for the same inner loop -> under the
// 128-VGPR / 16-waves-per-CU boundary without coercion.

#define LL   4096
#define DD   64
#define KK   512
#define NCB  4
#define NTHR 256

#define ZQ_ELEMS (32LL * NCB * DD * LL)   // 33,554,432 floats

// numpy pairwise sum of squares, n=64, exact op order (8 accumulators)
__device__ __forceinline__ float np_pairwise_sq64(const float* p) {
#pragma clang fp contract(off)
    float r[8];
#pragma unroll
    for (int j = 0; j < 8; ++j) { float s = p[j] * p[j]; r[j] = s; }
#pragma unroll
    for (int i = 8; i < 64; i += 8)
#pragma unroll
        for (int j = 0; j < 8; ++j) { float s = p[i + j] * p[i + j]; r[j] = r[j] + s; }
    return ((r[0] + r[1]) + (r[2] + r[3])) + ((r[4] + r[5]) + (r[6] + r[7]));
}

// ---------------- Kernel A: se[c][k] = np.sum(e*e, -1) ----------------
__global__ void se_kernel(const float* __restrict__ cb, float* __restrict__ se) {
    int t = blockIdx.x * blockDim.x + threadIdx.x;
    if (t >= NCB * KK) return;
    se[t] = np_pairwise_sq64(cb + (size_t)t * DD);
}

// ---------------- Main kernel ----------------
__global__ __launch_bounds__(NTHR) void rvq_kernel(const float* __restrict__ x_in,
                                                   const float* __restrict__ cb,
                                                   const float* __restrict__ se,
                                                   float* __restrict__ out) {
    __shared__ float zq_lds[2][DD][64];   // A-waves' z_q accumulator (32 KB)
    __shared__ float exv[4][64];          // argmin exchange: values
    __shared__ int   exi[4][64];          // argmin exchange: indices

    const int tid  = threadIdx.x;
    const int lane = tid & 63;
    const int wid  = tid >> 6;
    const int ts   = wid >> 1;     // token-set 0/1 within block
    const int half = wid & 1;      // k-half this wave scans

    const int tok = blockIdx.x * 128 + ts * 64 + lane;   // 1024 blocks x 128 tokens
    const int b   = tok >> 12;
    const int l   = tok & 4095;

    // ---- load this lane's token column: x[d] = x_in[b][d][l] (coalesced) ----
    float x[DD];
    {
        const float* xb = x_in + (size_t)b * DD * LL + l;
#pragma unroll
        for (int d = 0; d < DD; ++d) x[d] = xb[(size_t)d * LL];
    }

    // zero the zq accumulator (wave-private LDS slice; no barrier needed)
    if (half == 0) {
#pragma unroll
        for (int d = 0; d < DD; ++d) zq_lds[ts][d][lane] = 0.f;
    }

    const int kbase = half * 256;

#pragma unroll 1
    for (int c = 0; c < NCB; ++c) {
        // ---- sx: numpy pairwise sum of squares, lane-local, exact order ----
        float sxv;
        {
#pragma clang fp contract(off)
            float r[8];
#pragma unroll
            for (int j = 0; j < 8; ++j) { float s = x[j] * x[j]; r[j] = s; }
#pragma unroll
            for (int i = 8; i < 64; i += 8)
#pragma unroll
                for (int j = 0; j < 8; ++j) { float s = x[i + j] * x[i + j]; r[j] = r[j] + s; }
            sxv = ((r[0] + r[1]) + (r[2] + r[3])) + ((r[4] + r[5]) + (r[6] + r[7]));
        }

        float bestv = __builtin_inff();
        int   besti = kbase;

        // ---- half-codebook scan: 8 independent mul-init+FMA chains,
        // d4-major straight-line body (128 loads pipelined vs 512 FMAs).
        // Addresses are wave-uniform -> e/se scalarize to s_load. ----
#pragma unroll 1
        for (int k0 = kbase; k0 < kbase + 256; k0 += 8) {
            const float* ep = cb + ((size_t)(c * KK + k0)) * DD;
            float dot[8];
            {   // d4 = 0: mul-init (== fmaf into +0), then ascending fmaf
#pragma unroll
                for (int j = 0; j < 8; ++j) {
                    const float4 e = *reinterpret_cast<const float4*>(ep + j * DD);
                    dot[j] = x[0] * e.x;
                    dot[j] = fmaf(x[1], e.y, dot[j]);
                    dot[j] = fmaf(x[2], e.z, dot[j]);
                    dot[j] = fmaf(x[3], e.w, dot[j]);
                }
            }
#pragma unroll
            for (int d4 = 1; d4 < 16; ++d4) {
#pragma unroll
                for (int j = 0; j < 8; ++j) {
                    const float4 e = *reinterpret_cast<const float4*>(ep + j * DD + 4 * d4);
                    dot[j] = fmaf(x[4 * d4 + 0], e.x, dot[j]);
                    dot[j] = fmaf(x[4 * d4 + 1], e.y, dot[j]);
                    dot[j] = fmaf(x[4 * d4 + 2], e.z, dot[j]);
                    dot[j] = fmaf(x[4 * d4 + 3], e.w, dot[j]);
                }
            }

            // fold: d2 = (sx - 2*dot) + se, two f32 roundings, strict-< first-min
            {
#pragma clang fp contract(off)
                const float4 sa = *reinterpret_cast<const float4*>(se + c * KK + k0);
                const float4 sb = *reinterpret_cast<const float4*>(se + c * KK + k0 + 4);
                const float sev[8] = {sa.x, sa.y, sa.z, sa.w, sb.x, sb.y, sb.z, sb.w};
#pragma unroll
                for (int j = 0; j < 8; ++j) {
                    const float twod = 2.0f * dot[j];     // exact (x2)
                    const float d2 = (sxv - twod) + sev[j];
                    if (d2 < bestv) { bestv = d2; besti = k0 + j; }
                }
            }
        }

        // ---- cross-wave merge (A holds k<256, B holds k>=256).
        // take partner iff (ov < v) || (ov == v && oi < i) == global first-min ----
        exv[wid][lane] = bestv;
        exi[wid][lane] = besti;
        __syncthreads();
        {
            const float ov = exv[wid ^ 1][lane];
            const int   oi = exi[wid ^ 1][lane];
            if (ov < bestv || (ov == bestv && oi < besti)) { bestv = ov; besti = oi; }
        }
        __syncthreads();   // reads done before next cb's exchange writes

        // ---- residual update (both waves, keeps x copies identical) +
        // z_q accumulate/store (A-waves only, zq in LDS) ----
        {
#pragma clang fp contract(off)
            const float* er = cb + ((size_t)(c * KK) + besti) * DD;
            if (half == 0) {
                float* zo = out + (((size_t)b * NCB + c) * DD) * LL + l;
#pragma unroll
                for (int d4 = 0; d4 < DD; d4 += 4) {
                    const float4 ev = *reinterpret_cast<const float4*>(er + d4);
                    x[d4 + 0] = x[d4 + 0] - ev.x;
                    x[d4 + 1] = x[d4 + 1] - ev.y;
                    x[d4 + 2] = x[d4 + 2] - ev.z;
                    x[d4 + 3] = x[d4 + 3] - ev.w;
                    const float z0 = zq_lds[ts][d4 + 0][lane] + ev.x;
                    const float z1 = zq_lds[ts][d4 + 1][lane] + ev.y;
                    const float z2 = zq_lds[ts][d4 + 2][lane] + ev.z;
                    const float z3 = zq_lds[ts][d4 + 3][lane] + ev.w;
                    zq_lds[ts][d4 + 0][lane] = z0;  zo[(size_t)(d4 + 0) * LL] = z0;
                    zq_lds[ts][d4 + 1][lane] = z1;  zo[(size_t)(d4 + 1) * LL] = z1;
                    zq_lds[ts][d4 + 2][lane] = z2;  zo[(size_t)(d4 + 2) * LL] = z2;
                    zq_lds[ts][d4 + 3][lane] = z3;  zo[(size_t)(d4 + 3) * LL] = z3;
                }
                out[ZQ_ELEMS + ((size_t)b * LL + l) * NCB + c] = (float)besti;
            } else {
#pragma unroll
                for (int d4 = 0; d4 < DD; d4 += 4) {
                    const float4 ev = *reinterpret_cast<const float4*>(er + d4);
                    x[d4 + 0] = x[d4 + 0] - ev.x;
                    x[d4 + 1] = x[d4 + 1] - ev.y;
                    x[d4 + 2] = x[d4 + 2] - ev.z;
                    x[d4 + 3] = x[d4 + 3] - ev.w;
                }
            }
        }
    }
}

extern "C" void kernel_launch(void* const* d_in, const int* in_sizes, int n_in,
                              void* d_out, int out_size, void* d_ws, size_t ws_size,
                              hipStream_t stream) {
    const float* x_in = (const float*)d_in[0];
    const float* cb   = (const float*)d_in[1];
    float* out = (float*)d_out;
    float* se  = (float*)d_ws;   // NCB*KK floats = 8 KB scratch

    se_kernel<<<dim3((NCB * KK + 255) / 256), dim3(256), 0, stream>>>(cb, se);
    rvq_kernel<<<dim3((32 * LL) / 128), dim3(NTHR), 0, stream>>>(x_in, cb, se, out);
}

// Round 11
// 1307.511 us; speedup vs baseline: 1.5382x; 1.5382x over previous
//
#include <hip/hip_runtime.h>

// Residual VQ: B=32, D=64, L=4096, NCB=4, K=512.
// out: z_q_aggregated [B][NCB][D][L] f32, then indices [B][L][NCB] (as f32).
//
// Bit-exact reproduction of the reference float32 pipeline (validated absmax=0):
//   dot[t][k]: zero-init + single-accumulator FMA chain, d ascending 0..63
//   sx, se:    numpy pairwise 8-accumulator sum of squares, exact bracketing
//   d2 = (sx - 2*dot) + se     (two f32 roundings; 2*dot exact)
//   argmin:    first minimum (lowest k)
//   cascade:   x_res -= e[idx]; z_q += e[idx] in plain f32
//
// v11: T=16 tokens/wave (the only lever on the fixed e-LDS-per-FMA ratio that
// had v3 LDS-pipe-bound at 54% VALU) with the v5 register blowup removed:
//  - codebook staged via global_load_lds into [k'][4d] chunk tiles (linear
//    dest; bank spread via PRE-PERMUTED SOURCE: row r holds k'=((r&7)<<5)|(r>>3),
//    read at row R(k')=((k'&31)<<3)|(k'>>5) -> conflict-free ds_read_b128,
//    zero staging VGPRs, zero ds_writes)
//  - per-half fold+butterfly+park-to-LDS collapses b1v/b1i live range
//  - zq[16] in regs, z_q stored directly (no LDS staging, no extra barriers)
// LDS 50KB -> 3 blocks/CU (12 waves); VALU-bound by construction.

#define LL   4096
#define DD   64
#define KK   512
#define NCB  4
#define TB   64      // tokens per block
#define NTHR 256     // 4 waves; wave w owns tokens w*16..w*16+15
#define XS   68      // x_lds row stride (floats)

#define ZQ_ELEMS (32LL * NCB * DD * LL)   // 33,554,432 floats

// numpy pairwise sum of squares, n=64, exact op order (8 accumulators)
__device__ __forceinline__ float np_pairwise_sq64(const float* p) {
#pragma clang fp contract(off)
    float r[8];
#pragma unroll
    for (int j = 0; j < 8; ++j) { float s = p[j] * p[j]; r[j] = s; }
#pragma unroll
    for (int i = 8; i < 64; i += 8)
#pragma unroll
        for (int j = 0; j < 8; ++j) { float s = p[i + j] * p[i + j]; r[j] = r[j] + s; }
    return ((r[0] + r[1]) + (r[2] + r[3])) + ((r[4] + r[5]) + (r[6] + r[7]));
}

// ---------------- Kernel A: se[c][k] = np.sum(e*e, -1) ----------------
__global__ void se_kernel(const float* __restrict__ cb, float* __restrict__ se) {
    int t = blockIdx.x * blockDim.x + threadIdx.x;
    if (t >= NCB * KK) return;
    se[t] = np_pairwise_sq64(cb + (size_t)t * DD);
}

__device__ __forceinline__ void gload_lds16(const float* g, float* l) {
    __builtin_amdgcn_global_load_lds(
        (const __attribute__((address_space(1))) void*)g,
        (__attribute__((address_space(3))) void*)l, 16, 0, 0);
}

// ---------------- Main kernel ----------------
__global__ __launch_bounds__(NTHR) void rvq_kernel(const float* __restrict__ x_in,
                                                   const float* __restrict__ cb,
                                                   const float* __restrict__ se,
                                                   float* __restrict__ out) {
    __shared__ float ebuf[2][4096];     // dbuf: 4 chunks x [256 rows][4 d] each
    __shared__ float x_lds[DD * XS];    // residual [d][tok]
    __shared__ float pkv[4][2][16];     // per-wave per-half winner values
    __shared__ int   pki[4][2][16];     // per-wave per-half winner indices

    const int tid  = threadIdx.x;
    const int lane = tid & 63;
    const int wid  = tid >> 6;
    const int w16  = wid << 4;          // wave's first token

    const long T0 = (long)blockIdx.x * TB;
    const int b  = (int)(T0 >> 12);
    const int l0 = (int)(T0 & 4095);

    // ---- stage x tile: x_lds[d][tok] = x_in[b][d][l0+tok] ----
    {
        const float* xb = x_in + (size_t)b * DD * LL + l0;
#pragma unroll
        for (int it = 0; it < 4; ++it) {
            const int d = (tid >> 4) + it * 16;
            const int col = (tid & 15) << 2;
            const float4 v = *reinterpret_cast<const float4*>(xb + (size_t)d * LL + col);
            *reinterpret_cast<float4*>(&x_lds[d * XS + col]) = v;
        }
    }

    // ---- issue stage (c=0, s=0): wave wid stages its chunk (4 batches) ----
    {
        const float* gsrc = cb + (size_t)(wid * 4);           // h=0, m=0 -> dbase = wid*4
        float* ldst = &ebuf[0][wid * 1024];
#pragma unroll
        for (int q = 0; q < 4; ++q) {
            const int kq = ((lane & 7) << 5) | (q * 8) | (lane >> 3);
            gload_lds16(gsrc + (size_t)kq * DD, ldst + q * 256);
        }
    }

    // lane's 4 k-rows (within a 256-k half): k' = 4*lane + j, at permuted row
    const int k4 = lane << 2;
#define ROF(J) (((((k4 + (J)) & 31) << 3) | ((k4 + (J)) >> 5)) << 2)
    const int ro0 = ROF(0), ro1 = ROF(1), ro2 = ROF(2), ro3 = ROF(3);
#undef ROF

    const int sxj = lane & 7;    // pairwise accumulator index
    const int sxt = lane >> 3;   // token-in-group
    const int myt = lane & 15;   // own token within wave
    const int da  = lane >> 4;   // dim sub-index (0..3)

    __syncthreads();   // x_lds visible (also drains the stage-0 loads)

    float zq[16];
#pragma unroll
    for (int t = 0; t < 16; ++t) zq[t] = 0.f;

#pragma unroll 1
    for (int c = 0; c < NCB; ++c) {
        // ---- sx: lane-parallel numpy pairwise, two passes of 8 tokens ----
        float a3lo, a3hi;
        {
            float r;
            {
#pragma clang fp contract(off)
                float p = x_lds[sxj * XS + w16 + sxt];
                r = p * p;
#pragma unroll
                for (int i = 1; i < 8; ++i) {
                    float q = x_lds[(i * 8 + sxj) * XS + w16 + sxt];
                    r = r + q * q;
                }
            }
            float o1 = __shfl_xor(r, 1, 64);  float a1 = r + o1;
            float o2 = __shfl_xor(a1, 2, 64); float a2 = a1 + o2;
            float o4 = __shfl_xor(a2, 4, 64); a3lo = a2 + o4;
        }
        {
            float r;
            {
#pragma clang fp contract(off)
                float p = x_lds[sxj * XS + w16 + 8 + sxt];
                r = p * p;
#pragma unroll
                for (int i = 1; i < 8; ++i) {
                    float q = x_lds[(i * 8 + sxj) * XS + w16 + 8 + sxt];
                    r = r + q * q;
                }
            }
            float o1 = __shfl_xor(r, 1, 64);  float a1 = r + o1;
            float o2 = __shfl_xor(a1, 2, 64); float a2 = a1 + o2;
            float o4 = __shfl_xor(a2, 4, 64); a3hi = a2 + o4;
        }

        float acc[16][4];
        float b1v[16]; int b1i[16];

#pragma unroll 1
        for (int s = 0; s < 8; ++s) {        // s = h*4 + m
            __syncthreads();   // tile s ready (vmcnt drained); buf (s+1)&1 free

            // issue next stage's loads (async; land by the next barrier)
            {
                int nc = c, ns = s + 1;
                if (ns == 8) { nc = c + 1; ns = 0; }
                if (nc < NCB) {
                    const int dbase = (ns & 3) * 16 + wid * 4;
                    const float* gsrc = cb + ((size_t)(nc * KK + (ns >> 2) * 256)) * DD + dbase;
                    float* ldst = &ebuf[ns & 1][wid * 1024];
#pragma unroll
                    for (int q = 0; q < 4; ++q) {
                        const int kq = ((lane & 7) << 5) | (q * 8) | (lane >> 3);
                        gload_lds16(gsrc + (size_t)kq * DD, ldst + q * 256);
                    }
                }
            }

            const int m = s & 3;
            const int mbase = m * 16;
            if (m == 0) {   // half start: zero accumulators, reset argmin
#pragma unroll
                for (int t = 0; t < 16; ++t) {
                    b1v[t] = __builtin_inff(); b1i[t] = 0;
#pragma unroll
                    for (int g = 0; g < 4; ++g) acc[t][g] = 0.f;
                }
            }

            const float* eb = &ebuf[s & 1][0];

#define FM4(T, XV, E0, E1, E2, E3)               \
            acc[T][0] = fmaf(XV, E0, acc[T][0]); \
            acc[T][1] = fmaf(XV, E1, acc[T][1]); \
            acc[T][2] = fmaf(XV, E2, acc[T][2]); \
            acc[T][3] = fmaf(XV, E3, acc[T][3]);
#define FMA_DD(D, E0, E1, E2, E3) {                                                     \
            const float4 xa = *reinterpret_cast<const float4*>(&x_lds[(D) * XS + w16]);      \
            const float4 xb2 = *reinterpret_cast<const float4*>(&x_lds[(D) * XS + w16 + 4]); \
            const float4 xc = *reinterpret_cast<const float4*>(&x_lds[(D) * XS + w16 + 8]);  \
            const float4 xd = *reinterpret_cast<const float4*>(&x_lds[(D) * XS + w16 + 12]); \
            FM4(0, xa.x, E0, E1, E2, E3)  FM4(1, xa.y, E0, E1, E2, E3)                  \
            FM4(2, xa.z, E0, E1, E2, E3)  FM4(3, xa.w, E0, E1, E2, E3)                  \
            FM4(4, xb2.x, E0, E1, E2, E3) FM4(5, xb2.y, E0, E1, E2, E3)                 \
            FM4(6, xb2.z, E0, E1, E2, E3) FM4(7, xb2.w, E0, E1, E2, E3)                 \
            FM4(8, xc.x, E0, E1, E2, E3)  FM4(9, xc.y, E0, E1, E2, E3)                  \
            FM4(10, xc.z, E0, E1, E2, E3) FM4(11, xc.w, E0, E1, E2, E3)                 \
            FM4(12, xd.x, E0, E1, E2, E3) FM4(13, xd.y, E0, E1, E2, E3)                 \
            FM4(14, xd.z, E0, E1, E2, E3) FM4(15, xd.w, E0, E1, E2, E3) }

#pragma unroll
            for (int g = 0; g < 4; ++g) {
                const float* cbase = eb + g * 1024;
                const float4 e0 = *reinterpret_cast<const float4*>(cbase + ro0);
                const float4 e1 = *reinterpret_cast<const float4*>(cbase + ro1);
                const float4 e2 = *reinterpret_cast<const float4*>(cbase + ro2);
                const float4 e3 = *reinterpret_cast<const float4*>(cbase + ro3);
                const int d0 = mbase + g * 4;
                FMA_DD(d0 + 0, e0.x, e1.x, e2.x, e3.x)
                FMA_DD(d0 + 1, e0.y, e1.y, e2.y, e3.y)
                FMA_DD(d0 + 2, e0.z, e1.z, e2.z, e3.z)
                FMA_DD(d0 + 3, e0.w, e1.w, e2.w, e3.w)
            }
#undef FMA_DD
#undef FM4

            if (m == 3) {   // fold this k-half, butterfly, park
                const int h = s >> 2;
                {
#pragma clang fp contract(off)
                    const int kb = h * 256 + k4;
                    const float4 se4 = *reinterpret_cast<const float4*>(&se[c * KK + kb]);
                    const float sev[4] = {se4.x, se4.y, se4.z, se4.w};
#pragma unroll
                    for (int t = 0; t < 16; ++t) {
                        const float sxv = __shfl((t < 8) ? a3lo : a3hi, (t & 7) << 3, 64);
#pragma unroll
                        for (int g = 0; g < 4; ++g) {
                            const float twod = 2.0f * acc[t][g];      // exact (x2)
                            const float d2 = (sxv - twod) + sev[g];
                            if (d2 < b1v[t]) { b1v[t] = d2; b1i[t] = kb + g; }
                        }
                    }
                }
                // cross-lane argmin (butterfly), tie -> lower index
#pragma unroll
                for (int t = 0; t < 16; ++t) {
                    float v = b1v[t]; int i = b1i[t];
#pragma unroll
                    for (int off = 32; off > 0; off >>= 1) {
                        const float ov = __shfl_xor(v, off, 64);
                        const int   oi = __shfl_xor(i, off, 64);
                        if (ov < v || (ov == v && oi < i)) { v = ov; i = oi; }
                    }
                    b1v[t] = v; b1i[t] = i;
                }
                // park winners (wave-private LDS; b1 regs die here)
#pragma unroll
                for (int t = 0; t < 16; ++t)
                    if (lane == t) { pkv[wid][h][t] = b1v[t]; pki[wid][h][t] = b1i[t]; }
            }
        }

        // ---- merge halves (half-0 indices all lower -> tie takes half 0) ----
        const float v0 = pkv[wid][0][myt];  const int i0 = pki[wid][0][myt];
        const float v1 = pkv[wid][1][myt];  const int i1 = pki[wid][1][myt];
        const int kown = (v1 < v0) ? i1 : i0;

        // ---- residual update + z_q accumulate + direct store.
        // lane -> (tok = myt, d = i*4 + da); x_lds cells wave-private. ----
        {
#pragma clang fp contract(off)
            const float* er = cb + ((size_t)(c * KK) + kown) * DD + da;
            float* zo = out + (((size_t)b * NCB + c) * DD) * LL + l0 + w16 + myt;
#pragma unroll
            for (int i = 0; i < 16; ++i) {
                const float ev = er[i * 4];
                const int xi = (i * 4 + da) * XS + w16 + myt;
                x_lds[xi] = x_lds[xi] - ev;
                zq[i] = zq[i] + ev;
                zo[(size_t)(i * 4 + da) * LL] = zq[i];
            }
        }

        // indices (lanes 0..15 have myt == lane)
        if (lane < 16)
            out[ZQ_ELEMS + ((size_t)b * LL + l0 + w16 + lane) * NCB + c] = (float)kown;
    }
}

extern "C" void kernel_launch(void* const* d_in, const int* in_sizes, int n_in,
                              void* d_out, int out_size, void* d_ws, size_t ws_size,
                              hipStream_t stream) {
    const float* x_in = (const float*)d_in[0];
    const float* cb   = (const float*)d_in[1];
    float* out = (float*)d_out;
    float* se  = (float*)d_ws;   // NCB*KK floats = 8 KB scratch

    se_kernel<<<dim3((NCB * KK + 255) / 256), dim3(256), 0, stream>>>(cb, se);
    rvq_kernel<<<dim3((32 * LL) / TB), dim3(NTHR), 0, stream>>>(x_in, cb, se, out);
}